// Round 4
// baseline (380.972 us; speedup 1.0000x reference)
//
#include <hip/hip_runtime.h>
#include <hip/hip_bf16.h>

#define NN 10000
#define EE 320000
#define ET (EE + NN)      // 330000 edges incl self-loops
#define FIN 256
#define HD 128
#define NEG 0.2f

// Inputs fp32, edge_index int32, OUTPUT fp32 (reference returns jnp.float32).

// ---------------- CSR build (counting sort by dst) ----------------

__global__ void k_zero_i(int* __restrict__ p, int n) {
    int i = blockIdx.x * blockDim.x + threadIdx.x;
    if (i < n) p[i] = 0;
}

__global__ void k_hist(const int* __restrict__ ei, int* __restrict__ counts) {
    int i = blockIdx.x * blockDim.x + threadIdx.x;
    if (i >= ET) return;
    int d = (i < EE) ? ei[EE + i] : (i - EE);
    atomicAdd(&counts[d], 1);
}

// single 256-thread block: exclusive scan counts[NN] -> offsets[NN+1], cursor[NN]
__global__ void k_scan(const int* __restrict__ counts,
                       int* __restrict__ offsets,
                       int* __restrict__ cursor) {
    const int CHUNK = 40;   // 256*40 = 10240 >= 10000
    __shared__ int sums[256];
    int t = threadIdx.x;
    int base = t * CHUNK;
    int s = 0;
    for (int i = 0; i < CHUNK; i++) {
        int idx = base + i;
        if (idx < NN) s += counts[idx];
    }
    sums[t] = s;
    __syncthreads();
    for (int off = 1; off < 256; off <<= 1) {
        int v = (t >= off) ? sums[t - off] : 0;
        __syncthreads();
        sums[t] += v;
        __syncthreads();
    }
    int run = (t > 0) ? sums[t - 1] : 0;
    for (int i = 0; i < CHUNK; i++) {
        int idx = base + i;
        if (idx < NN) {
            offsets[idx] = run;
            cursor[idx]  = run;
            run += counts[idx];
        }
    }
    if (t == 255) offsets[NN] = sums[255];
}

__global__ void k_scatter(const int* __restrict__ ei, int* __restrict__ cursor,
                          int* __restrict__ elist) {
    int i = blockIdx.x * blockDim.x + threadIdx.x;
    if (i >= ET) return;
    int d = (i < EE) ? ei[EE + i] : (i - EE);
    int pos = atomicAdd(&cursor[d], 1);
    elist[pos] = i;
}

// ---------------- GEMM layer 1: h = x @ W1 (K=256), + a_s, a_d ----------------

__global__ void k_gemm1(const float* __restrict__ xin,
                        const float* __restrict__ W,
                        const float* __restrict__ atts,
                        const float* __restrict__ attd,
                        float* __restrict__ h,
                        float* __restrict__ a_s,
                        float* __restrict__ a_d) {
    __shared__ float xs[FIN];
    __shared__ float red[128];
    int node = blockIdx.x;
    int t = threadIdx.x;
    xs[t]       = xin[(size_t)node * FIN + t];
    xs[t + 128] = xin[(size_t)node * FIN + t + 128];
    __syncthreads();
    float acc = 0.f;
    #pragma unroll 8
    for (int k = 0; k < FIN; k++) acc += xs[k] * W[k * HD + t];
    h[(size_t)node * HD + t] = acc;

    float vs = acc * atts[t];
    float vd = acc * attd[t];
    red[t] = vs;
    __syncthreads();
    for (int off = 64; off > 0; off >>= 1) {
        if (t < off) red[t] += red[t + off];
        __syncthreads();
    }
    if (t == 0) a_s[node] = red[0];
    __syncthreads();
    red[t] = vd;
    __syncthreads();
    for (int off = 64; off > 0; off >>= 1) {
        if (t < off) red[t] += red[t + off];
        __syncthreads();
    }
    if (t == 0) a_d[node] = red[0];
}

// ---------------- GEMM layer 2: h = g1 @ W2 (K=128), + a_s, a_d ----------------

__global__ void k_gemm2(const float* __restrict__ xin,
                        const float* __restrict__ W,
                        const float* __restrict__ atts,
                        const float* __restrict__ attd,
                        float* __restrict__ h,
                        float* __restrict__ a_s,
                        float* __restrict__ a_d) {
    __shared__ float xs[HD];
    __shared__ float red[128];
    int node = blockIdx.x;
    int t = threadIdx.x;
    xs[t] = xin[(size_t)node * HD + t];
    __syncthreads();
    float acc = 0.f;
    #pragma unroll 8
    for (int k = 0; k < HD; k++) acc += xs[k] * W[k * HD + t];
    h[(size_t)node * HD + t] = acc;

    float vs = acc * atts[t];
    float vd = acc * attd[t];
    red[t] = vs;
    __syncthreads();
    for (int off = 64; off > 0; off >>= 1) {
        if (t < off) red[t] += red[t + off];
        __syncthreads();
    }
    if (t == 0) a_s[node] = red[0];
    __syncthreads();
    red[t] = vd;
    __syncthreads();
    for (int off = 64; off > 0; off >>= 1) {
        if (t < off) red[t] += red[t + off];
        __syncthreads();
    }
    if (t == 0) a_d[node] = red[0];
}

// ---------------- per-edge exp(leaky_relu(a_s[src] + a_d[dst])) ----------------
// Max-subtraction skipped: alpha is shift-invariant and e is O(1) here.

__global__ void k_exps(const int* __restrict__ ei, const float* __restrict__ a_s,
                       const float* __restrict__ a_d, float* __restrict__ exps) {
    int i = blockIdx.x * blockDim.x + threadIdx.x;
    if (i >= ET) return;
    int s, d;
    if (i < EE) { s = ei[i]; d = ei[EE + i]; }
    else        { s = i - EE; d = s; }
    float e = a_s[s] + a_d[d];
    e = (e > 0.f) ? e : NEG * e;
    exps[i] = expf(e);
}

// ---------------- aggregation: one block per dst node, no atomics ----------------
// z > 0 structurally: every node has a self-loop.

__global__ void k_agg1(const int* __restrict__ offsets,
                       const int* __restrict__ elist,
                       const int* __restrict__ ei,
                       const float* __restrict__ exps,
                       const float* __restrict__ h,
                       const float* __restrict__ bias,
                       float* __restrict__ g) {
    int node = blockIdx.x;
    int t = threadIdx.x;
    int beg = offsets[node], end = offsets[node + 1];
    float acc = 0.f, z = 0.f;
    for (int p = beg; p < end; p++) {
        int eid = elist[p];
        int s = (eid < EE) ? ei[eid] : (eid - EE);
        float ex = exps[eid];
        z += ex;
        acc += ex * h[(size_t)s * HD + t];
    }
    float o = acc / z + bias[t];
    g[(size_t)node * HD + t] = (o > 0.f) ? o : 0.f;   // relu
}

// layer-2 aggregation fused with reduce_dim: r[n] = relu(agg+b2) . Wr + br
__global__ void k_agg2(const int* __restrict__ offsets,
                       const int* __restrict__ elist,
                       const int* __restrict__ ei,
                       const float* __restrict__ exps,
                       const float* __restrict__ h,
                       const float* __restrict__ bias,
                       const float* __restrict__ Wr,
                       const float* __restrict__ br,
                       float* __restrict__ r) {
    __shared__ float red[128];
    int node = blockIdx.x;
    int t = threadIdx.x;
    int beg = offsets[node], end = offsets[node + 1];
    float acc = 0.f, z = 0.f;
    for (int p = beg; p < end; p++) {
        int eid = elist[p];
        int s = (eid < EE) ? ei[eid] : (eid - EE);
        float ex = exps[eid];
        z += ex;
        acc += ex * h[(size_t)s * HD + t];
    }
    float o = acc / z + bias[t];
    o = (o > 0.f) ? o : 0.f;
    red[t] = o * Wr[t];
    __syncthreads();
    for (int off = 64; off > 0; off >>= 1) {
        if (t < off) red[t] += red[t + off];
        __syncthreads();
    }
    if (t == 0) r[node] = red[0] + br[0];
}

// ---------------- classifier: out[c] = sum_n r[n]*Wc[n,c] + bc[c] ----------------

__global__ void k_cls(const float* __restrict__ r,
                      const float* __restrict__ Wc,
                      const float* __restrict__ bc,
                      float* __restrict__ out) {
    __shared__ float r0[256], r1[256];
    int t = threadIdx.x;
    float c0 = 0.f, c1 = 0.f;
    for (int n = t; n < NN; n += 256) {
        float rv = r[n];
        c0 += rv * Wc[2 * n];
        c1 += rv * Wc[2 * n + 1];
    }
    r0[t] = c0; r1[t] = c1;
    __syncthreads();
    for (int off = 128; off > 0; off >>= 1) {
        if (t < off) { r0[t] += r0[t + off]; r1[t] += r1[t + off]; }
        __syncthreads();
    }
    if (t == 0) {
        out[0] = r0[0] + bc[0];   // fp32 output, per reference dtype
        out[1] = r1[0] + bc[1];
    }
}

// ---------------- launch ----------------

extern "C" void kernel_launch(void* const* d_in, const int* in_sizes, int n_in,
                              void* d_out, int out_size, void* d_ws, size_t ws_size,
                              hipStream_t stream) {
    const float* x    = (const float*)d_in[0];
    const int*   ei   = (const int*)d_in[1];
    const float* W1   = (const float*)d_in[2];
    const float* as1  = (const float*)d_in[3];
    const float* ad1  = (const float*)d_in[4];
    const float* b1   = (const float*)d_in[5];
    const float* W2   = (const float*)d_in[6];
    const float* as2  = (const float*)d_in[7];
    const float* ad2  = (const float*)d_in[8];
    const float* b2   = (const float*)d_in[9];
    const float* Wr   = (const float*)d_in[10];
    const float* br   = (const float*)d_in[11];
    const float* Wc   = (const float*)d_in[12];
    const float* bc   = (const float*)d_in[13];
    float* out = (float*)d_out;

    // workspace layout (floats then ints), ~13.2 MB total
    float* h    = (float*)d_ws;                  // NN*HD
    float* g1   = h + (size_t)NN * HD;           // NN*HD
    float* exps = g1 + (size_t)NN * HD;          // ET
    float* a_s  = exps + ET;                     // NN
    float* a_d  = a_s + NN;                      // NN
    float* r    = a_d + NN;                      // NN
    int* counts  = (int*)(r + NN);               // NN
    int* offsets = counts + NN;                  // NN+1
    int* cursor  = offsets + NN + 1;             // NN
    int* elist   = cursor + NN;                  // ET

    const int TPB = 256;
    const int gET = (ET + TPB - 1) / TPB;
    const int gNN = (NN + TPB - 1) / TPB;

    // CSR build (shared by both layers)
    k_zero_i<<<gNN, TPB, 0, stream>>>(counts, NN);
    k_hist<<<gET, TPB, 0, stream>>>(ei, counts);
    k_scan<<<1, 256, 0, stream>>>(counts, offsets, cursor);
    k_scatter<<<gET, TPB, 0, stream>>>(ei, cursor, elist);

    // layer 1
    k_gemm1<<<NN, 128, 0, stream>>>(x, W1, as1, ad1, h, a_s, a_d);
    k_exps<<<gET, TPB, 0, stream>>>(ei, a_s, a_d, exps);
    k_agg1<<<NN, 128, 0, stream>>>(offsets, elist, ei, exps, h, b1, g1);

    // layer 2
    k_gemm2<<<NN, 128, 0, stream>>>(g1, W2, as2, ad2, h, a_s, a_d);
    k_exps<<<gET, TPB, 0, stream>>>(ei, a_s, a_d, exps);
    k_agg2<<<NN, 128, 0, stream>>>(offsets, elist, ei, exps, h, b2, Wr, br, r);

    // classifier
    k_cls<<<1, 256, 0, stream>>>(r, Wc, bc, out);
}

// Round 5
// 266.286 us; speedup vs baseline: 1.4307x; 1.4307x over previous
//
#include <hip/hip_runtime.h>
#include <hip/hip_bf16.h>

#define NN 10000
#define EE 320000
#define ET (EE + NN)      // 330000 edges incl self-loops
#define FIN 256
#define HD 128
#define NEG 0.2f

// Inputs fp32, edge_index int32, OUTPUT fp32.

// ---------------- CSR build (counting sort by dst) ----------------

__global__ void k_zero_i(int* __restrict__ p, int n) {
    int i = blockIdx.x * blockDim.x + threadIdx.x;
    if (i < n) p[i] = 0;
}

__global__ void k_hist(const int* __restrict__ ei, int* __restrict__ counts) {
    int i = blockIdx.x * blockDim.x + threadIdx.x;
    if (i >= ET) return;
    int d = (i < EE) ? ei[EE + i] : (i - EE);
    atomicAdd(&counts[d], 1);
}

// single 256-thread block: exclusive scan counts[NN] -> offsets[NN+1], cursor[NN]
__global__ void k_scan(const int* __restrict__ counts,
                       int* __restrict__ offsets,
                       int* __restrict__ cursor) {
    const int CHUNK = 40;   // 256*40 = 10240 >= 10000
    __shared__ int sums[256];
    int t = threadIdx.x;
    int base = t * CHUNK;
    int s = 0;
    for (int i = 0; i < CHUNK; i++) {
        int idx = base + i;
        if (idx < NN) s += counts[idx];
    }
    sums[t] = s;
    __syncthreads();
    for (int off = 1; off < 256; off <<= 1) {
        int v = (t >= off) ? sums[t - off] : 0;
        __syncthreads();
        sums[t] += v;
        __syncthreads();
    }
    int run = (t > 0) ? sums[t - 1] : 0;
    for (int i = 0; i < CHUNK; i++) {
        int idx = base + i;
        if (idx < NN) {
            offsets[idx] = run;
            cursor[idx]  = run;
            run += counts[idx];
        }
    }
    if (t == 255) offsets[NN] = sums[255];
}

// scatter stores the SOURCE node id in CSR position (depth-1 gather chain in agg)
__global__ void k_scatter(const int* __restrict__ ei, int* __restrict__ cursor,
                          int* __restrict__ srclist) {
    int i = blockIdx.x * blockDim.x + threadIdx.x;
    if (i >= ET) return;
    int s, d;
    if (i < EE) { s = ei[i]; d = ei[EE + i]; }
    else        { s = i - EE; d = s; }
    int pos = atomicAdd(&cursor[d], 1);
    srclist[pos] = s;
}

// ---------------- GEMM layer 1: h = x @ W1 (K=256), M-tiled by 8 ----------------
// block = 128 threads (thread owns feature t), 8 nodes per block.
// W value W[k][t] reused across the 8 accumulators -> W L2 traffic /8.

__global__ void k_gemm1(const float* __restrict__ x,
                        const float* __restrict__ W,
                        const float* __restrict__ atts,
                        const float* __restrict__ attd,
                        float* __restrict__ h,
                        float* __restrict__ a_s,
                        float* __restrict__ a_d) {
    __shared__ float xs[8 * FIN];   // 8 KB
    __shared__ float red[4];
    int t = threadIdx.x;
    int m0 = blockIdx.x * 8;        // 1250 blocks
    const float4* xv = (const float4*)(x + (size_t)m0 * FIN);
    float4* xsv = (float4*)xs;
    #pragma unroll
    for (int i = 0; i < 4; i++)     // 8*256/4 = 512 float4 / 128 threads
        xsv[t + 128 * i] = xv[t + 128 * i];
    __syncthreads();

    float acc[8] = {0.f,0.f,0.f,0.f,0.f,0.f,0.f,0.f};
    for (int k = 0; k < FIN; k += 4) {
        float w0 = W[(k + 0) * HD + t];
        float w1 = W[(k + 1) * HD + t];
        float w2 = W[(k + 2) * HD + t];
        float w3 = W[(k + 3) * HD + t];
        #pragma unroll
        for (int m = 0; m < 8; m++) {
            float4 xk = *(const float4*)&xs[m * FIN + k];
            acc[m] += xk.x * w0;
            acc[m] += xk.y * w1;
            acc[m] += xk.z * w2;
            acc[m] += xk.w * w3;
        }
    }

    float at_s = atts[t], at_d = attd[t];
    int lane = t & 63, wid = t >> 6;
    #pragma unroll
    for (int m = 0; m < 8; m++) {
        h[(size_t)(m0 + m) * HD + t] = acc[m];
        float vs = acc[m] * at_s, vd = acc[m] * at_d;
        #pragma unroll
        for (int off = 32; off > 0; off >>= 1) {
            vs += __shfl_down(vs, off);
            vd += __shfl_down(vd, off);
        }
        if (lane == 0) { red[wid] = vs; red[2 + wid] = vd; }
        __syncthreads();
        if (t == 0) {
            a_s[m0 + m] = red[0] + red[1];
            a_d[m0 + m] = red[2] + red[3];
        }
        __syncthreads();
    }
}

// ---------------- GEMM layer 2: h = g1 @ W2 (K=128), M-tiled by 8 ----------------

__global__ void k_gemm2(const float* __restrict__ x,
                        const float* __restrict__ W,
                        const float* __restrict__ atts,
                        const float* __restrict__ attd,
                        float* __restrict__ h,
                        float* __restrict__ a_s,
                        float* __restrict__ a_d) {
    __shared__ float xs[8 * HD];    // 4 KB
    __shared__ float red[4];
    int t = threadIdx.x;
    int m0 = blockIdx.x * 8;
    const float4* xv = (const float4*)(x + (size_t)m0 * HD);
    float4* xsv = (float4*)xs;
    #pragma unroll
    for (int i = 0; i < 2; i++)     // 8*128/4 = 256 float4 / 128 threads
        xsv[t + 128 * i] = xv[t + 128 * i];
    __syncthreads();

    float acc[8] = {0.f,0.f,0.f,0.f,0.f,0.f,0.f,0.f};
    for (int k = 0; k < HD; k += 4) {
        float w0 = W[(k + 0) * HD + t];
        float w1 = W[(k + 1) * HD + t];
        float w2 = W[(k + 2) * HD + t];
        float w3 = W[(k + 3) * HD + t];
        #pragma unroll
        for (int m = 0; m < 8; m++) {
            float4 xk = *(const float4*)&xs[m * HD + k];
            acc[m] += xk.x * w0;
            acc[m] += xk.y * w1;
            acc[m] += xk.z * w2;
            acc[m] += xk.w * w3;
        }
    }

    float at_s = atts[t], at_d = attd[t];
    int lane = t & 63, wid = t >> 6;
    #pragma unroll
    for (int m = 0; m < 8; m++) {
        h[(size_t)(m0 + m) * HD + t] = acc[m];
        float vs = acc[m] * at_s, vd = acc[m] * at_d;
        #pragma unroll
        for (int off = 32; off > 0; off >>= 1) {
            vs += __shfl_down(vs, off);
            vd += __shfl_down(vd, off);
        }
        if (lane == 0) { red[wid] = vs; red[2 + wid] = vd; }
        __syncthreads();
        if (t == 0) {
            a_s[m0 + m] = red[0] + red[1];
            a_d[m0 + m] = red[2] + red[3];
        }
        __syncthreads();
    }
}

// ---------------- aggregation: block per dst node, exp fused, 4-way unrolled ----
// alpha softmax: max-subtraction skipped (shift-invariant; e is O(1) here).
// z > 0 structurally (self-loop per node).

__device__ __forceinline__ float edge_exp(float as_v, float adn) {
    float e = as_v + adn;
    e = (e > 0.f) ? e : NEG * e;
    return expf(e);
}

__global__ void k_agg1(const int* __restrict__ offsets,
                       const int* __restrict__ srclist,
                       const float* __restrict__ a_s,
                       const float* __restrict__ a_d,
                       const float* __restrict__ h,
                       const float* __restrict__ bias,
                       float* __restrict__ g) {
    int node = blockIdx.x;
    int t = threadIdx.x;
    int beg = offsets[node], end = offsets[node + 1];
    float adn = a_d[node];
    float acc = 0.f, z = 0.f;
    int p = beg;
    for (; p + 4 <= end; p += 4) {
        int s0 = srclist[p], s1 = srclist[p + 1], s2 = srclist[p + 2], s3 = srclist[p + 3];
        float h0 = h[(size_t)s0 * HD + t];
        float h1 = h[(size_t)s1 * HD + t];
        float h2 = h[(size_t)s2 * HD + t];
        float h3 = h[(size_t)s3 * HD + t];
        float x0 = edge_exp(a_s[s0], adn);
        float x1 = edge_exp(a_s[s1], adn);
        float x2 = edge_exp(a_s[s2], adn);
        float x3 = edge_exp(a_s[s3], adn);
        z += x0 + x1 + x2 + x3;
        acc += x0 * h0 + x1 * h1 + x2 * h2 + x3 * h3;
    }
    for (; p < end; p++) {
        int s = srclist[p];
        float hv = h[(size_t)s * HD + t];
        float ex = edge_exp(a_s[s], adn);
        z += ex;
        acc += ex * hv;
    }
    float o = acc / z + bias[t];
    g[(size_t)node * HD + t] = (o > 0.f) ? o : 0.f;   // relu
}

// layer-2 aggregation fused with reduce_dim: r[n] = relu(agg+b2) . Wr + br
__global__ void k_agg2(const int* __restrict__ offsets,
                       const int* __restrict__ srclist,
                       const float* __restrict__ a_s,
                       const float* __restrict__ a_d,
                       const float* __restrict__ h,
                       const float* __restrict__ bias,
                       const float* __restrict__ Wr,
                       const float* __restrict__ br,
                       float* __restrict__ r) {
    __shared__ float red[128];
    int node = blockIdx.x;
    int t = threadIdx.x;
    int beg = offsets[node], end = offsets[node + 1];
    float adn = a_d[node];
    float acc = 0.f, z = 0.f;
    int p = beg;
    for (; p + 4 <= end; p += 4) {
        int s0 = srclist[p], s1 = srclist[p + 1], s2 = srclist[p + 2], s3 = srclist[p + 3];
        float h0 = h[(size_t)s0 * HD + t];
        float h1 = h[(size_t)s1 * HD + t];
        float h2 = h[(size_t)s2 * HD + t];
        float h3 = h[(size_t)s3 * HD + t];
        float x0 = edge_exp(a_s[s0], adn);
        float x1 = edge_exp(a_s[s1], adn);
        float x2 = edge_exp(a_s[s2], adn);
        float x3 = edge_exp(a_s[s3], adn);
        z += x0 + x1 + x2 + x3;
        acc += x0 * h0 + x1 * h1 + x2 * h2 + x3 * h3;
    }
    for (; p < end; p++) {
        int s = srclist[p];
        float hv = h[(size_t)s * HD + t];
        float ex = edge_exp(a_s[s], adn);
        z += ex;
        acc += ex * hv;
    }
    float o = acc / z + bias[t];
    o = (o > 0.f) ? o : 0.f;
    red[t] = o * Wr[t];
    __syncthreads();
    for (int off = 64; off > 0; off >>= 1) {
        if (t < off) red[t] += red[t + off];
        __syncthreads();
    }
    if (t == 0) r[node] = red[0] + br[0];
}

// ---------------- classifier: out[c] = sum_n r[n]*Wc[n,c] + bc[c] ----------------

__global__ void k_cls(const float* __restrict__ r,
                      const float* __restrict__ Wc,
                      const float* __restrict__ bc,
                      float* __restrict__ out) {
    __shared__ float r0[256], r1[256];
    int t = threadIdx.x;
    float c0 = 0.f, c1 = 0.f;
    for (int n = t; n < NN; n += 256) {
        float rv = r[n];
        c0 += rv * Wc[2 * n];
        c1 += rv * Wc[2 * n + 1];
    }
    r0[t] = c0; r1[t] = c1;
    __syncthreads();
    for (int off = 128; off > 0; off >>= 1) {
        if (t < off) { r0[t] += r0[t + off]; r1[t] += r1[t + off]; }
        __syncthreads();
    }
    if (t == 0) {
        out[0] = r0[0] + bc[0];
        out[1] = r1[0] + bc[1];
    }
}

// ---------------- launch ----------------

extern "C" void kernel_launch(void* const* d_in, const int* in_sizes, int n_in,
                              void* d_out, int out_size, void* d_ws, size_t ws_size,
                              hipStream_t stream) {
    const float* x    = (const float*)d_in[0];
    const int*   ei   = (const int*)d_in[1];
    const float* W1   = (const float*)d_in[2];
    const float* as1  = (const float*)d_in[3];
    const float* ad1  = (const float*)d_in[4];
    const float* b1   = (const float*)d_in[5];
    const float* W2   = (const float*)d_in[6];
    const float* as2  = (const float*)d_in[7];
    const float* ad2  = (const float*)d_in[8];
    const float* b2   = (const float*)d_in[9];
    const float* Wr   = (const float*)d_in[10];
    const float* br   = (const float*)d_in[11];
    const float* Wc   = (const float*)d_in[12];
    const float* bc   = (const float*)d_in[13];
    float* out = (float*)d_out;

    // workspace layout
    float* h    = (float*)d_ws;                  // NN*HD
    float* g1   = h + (size_t)NN * HD;           // NN*HD
    float* a_s  = g1 + (size_t)NN * HD;          // NN
    float* a_d  = a_s + NN;                      // NN
    float* r    = a_d + NN;                      // NN
    int* counts  = (int*)(r + NN);               // NN
    int* offsets = counts + NN;                  // NN+1
    int* cursor  = offsets + NN + 1;             // NN
    int* srclist = cursor + NN;                  // ET

    const int TPB = 256;
    const int gET = (ET + TPB - 1) / TPB;
    const int gNN = (NN + TPB - 1) / TPB;

    // CSR build (shared by both layers)
    k_zero_i<<<gNN, TPB, 0, stream>>>(counts, NN);
    k_hist<<<gET, TPB, 0, stream>>>(ei, counts);
    k_scan<<<1, 256, 0, stream>>>(counts, offsets, cursor);
    k_scatter<<<gET, TPB, 0, stream>>>(ei, cursor, srclist);

    // layer 1
    k_gemm1<<<NN / 8, 128, 0, stream>>>(x, W1, as1, ad1, h, a_s, a_d);
    k_agg1<<<NN, 128, 0, stream>>>(offsets, srclist, a_s, a_d, h, b1, g1);

    // layer 2
    k_gemm2<<<NN / 8, 128, 0, stream>>>(g1, W2, as2, ad2, h, a_s, a_d);
    k_agg2<<<NN, 128, 0, stream>>>(offsets, srclist, a_s, a_d, h, b2, Wr, br, r);

    // classifier
    k_cls<<<1, 256, 0, stream>>>(r, Wc, bc, out);
}

// Round 6
// 249.936 us; speedup vs baseline: 1.5243x; 1.0654x over previous
//
#include <hip/hip_runtime.h>
#include <hip/hip_bf16.h>

#define NN 10000
#define EE 320000
#define ET (EE + NN)      // 330000 edges incl self-loops
#define FIN 256
#define HD 128
#define NEG 0.2f

// Inputs fp32, edge_index int32, OUTPUT fp32.

// ---------------- CSR build (counting sort by dst) ----------------

__global__ void k_zero_i(int* __restrict__ p, int n) {
    int i = blockIdx.x * blockDim.x + threadIdx.x;
    if (i < n) p[i] = 0;
}

__global__ void k_hist(const int* __restrict__ ei, int* __restrict__ counts) {
    int i = blockIdx.x * blockDim.x + threadIdx.x;
    if (i >= ET) return;
    int d = (i < EE) ? ei[EE + i] : (i - EE);
    atomicAdd(&counts[d], 1);
}

// single 256-thread block: exclusive scan counts[NN] -> offsets[NN+1], cursor[NN]
__global__ void k_scan(const int* __restrict__ counts,
                       int* __restrict__ offsets,
                       int* __restrict__ cursor) {
    const int CHUNK = 40;   // 256*40 = 10240 >= 10000
    __shared__ int sums[256];
    int t = threadIdx.x;
    int base = t * CHUNK;
    int s = 0;
    for (int i = 0; i < CHUNK; i++) {
        int idx = base + i;
        if (idx < NN) s += counts[idx];
    }
    sums[t] = s;
    __syncthreads();
    for (int off = 1; off < 256; off <<= 1) {
        int v = (t >= off) ? sums[t - off] : 0;
        __syncthreads();
        sums[t] += v;
        __syncthreads();
    }
    int run = (t > 0) ? sums[t - 1] : 0;
    for (int i = 0; i < CHUNK; i++) {
        int idx = base + i;
        if (idx < NN) {
            offsets[idx] = run;
            cursor[idx]  = run;
            run += counts[idx];
        }
    }
    if (t == 255) offsets[NN] = sums[255];
}

// scatter stores the SOURCE node id at the CSR position
__global__ void k_scatter(const int* __restrict__ ei, int* __restrict__ cursor,
                          int* __restrict__ srclist) {
    int i = blockIdx.x * blockDim.x + threadIdx.x;
    if (i >= ET) return;
    int s, d;
    if (i < EE) { s = ei[i]; d = ei[EE + i]; }
    else        { s = i - EE; d = s; }
    int pos = atomicAdd(&cursor[d], 1);
    srclist[pos] = s;
}

// ---------------- GEMM layer 1: h = x @ W1 (K=256) ----------------
// 128 threads = 2 wave-groups; group g handles 8 nodes, thread owns 2 features.
// One ds_read_b128 (x broadcast) feeds 8 FMAs -> compute-bound, not LDS-bound.

__global__ void k_gemm1(const float* __restrict__ x,
                        const float* __restrict__ W,
                        const float* __restrict__ atts,
                        const float* __restrict__ attd,
                        float* __restrict__ h,
                        float* __restrict__ a_s,
                        float* __restrict__ a_d) {
    __shared__ float xs[16 * FIN];   // 16 KB
    int t = threadIdx.x;
    int m0 = blockIdx.x * 16;        // 625 blocks
    const float4* xv = (const float4*)(x + (size_t)m0 * FIN);
    float4* xsv = (float4*)xs;
    #pragma unroll
    for (int i = 0; i < 8; i++)      // 16*256/4 = 1024 float4 / 128 threads
        xsv[t + 128 * i] = xv[t + 128 * i];
    __syncthreads();

    int g = t >> 6;                  // wave-group = node-group
    int tt = t & 63;
    int f = tt * 2;                  // feature pair
    const float* xg = xs + g * 8 * FIN;

    float2 acc[8];
    #pragma unroll
    for (int m = 0; m < 8; m++) acc[m] = make_float2(0.f, 0.f);

    for (int k = 0; k < FIN; k += 4) {
        float2 w0 = *(const float2*)&W[(k + 0) * HD + f];
        float2 w1 = *(const float2*)&W[(k + 1) * HD + f];
        float2 w2 = *(const float2*)&W[(k + 2) * HD + f];
        float2 w3 = *(const float2*)&W[(k + 3) * HD + f];
        #pragma unroll
        for (int m = 0; m < 8; m++) {
            float4 xk = *(const float4*)&xg[m * FIN + k];
            acc[m].x += xk.x * w0.x; acc[m].y += xk.x * w0.y;
            acc[m].x += xk.y * w1.x; acc[m].y += xk.y * w1.y;
            acc[m].x += xk.z * w2.x; acc[m].y += xk.z * w2.y;
            acc[m].x += xk.w * w3.x; acc[m].y += xk.w * w3.y;
        }
    }

    float2 ats = *(const float2*)&atts[f];
    float2 atd = *(const float2*)&attd[f];
    #pragma unroll
    for (int m = 0; m < 8; m++) {
        int node = m0 + g * 8 + m;
        *(float2*)&h[(size_t)node * HD + f] = acc[m];
        float vs = acc[m].x * ats.x + acc[m].y * ats.y;
        float vd = acc[m].x * atd.x + acc[m].y * atd.y;
        #pragma unroll
        for (int off = 32; off > 0; off >>= 1) {
            vs += __shfl_down(vs, off);
            vd += __shfl_down(vd, off);
        }
        if (tt == 0) { a_s[node] = vs; a_d[node] = vd; }
    }
}

// ---------------- GEMM layer 2: h = g1 @ W2 (K=128), same structure ----------------

__global__ void k_gemm2(const float* __restrict__ x,
                        const float* __restrict__ W,
                        const float* __restrict__ atts,
                        const float* __restrict__ attd,
                        float* __restrict__ h,
                        float* __restrict__ a_s,
                        float* __restrict__ a_d) {
    __shared__ float xs[16 * HD];    // 8 KB
    int t = threadIdx.x;
    int m0 = blockIdx.x * 16;
    const float4* xv = (const float4*)(x + (size_t)m0 * HD);
    float4* xsv = (float4*)xs;
    #pragma unroll
    for (int i = 0; i < 4; i++)      // 16*128/4 = 512 float4 / 128 threads
        xsv[t + 128 * i] = xv[t + 128 * i];
    __syncthreads();

    int g = t >> 6;
    int tt = t & 63;
    int f = tt * 2;
    const float* xg = xs + g * 8 * HD;

    float2 acc[8];
    #pragma unroll
    for (int m = 0; m < 8; m++) acc[m] = make_float2(0.f, 0.f);

    for (int k = 0; k < HD; k += 4) {
        float2 w0 = *(const float2*)&W[(k + 0) * HD + f];
        float2 w1 = *(const float2*)&W[(k + 1) * HD + f];
        float2 w2 = *(const float2*)&W[(k + 2) * HD + f];
        float2 w3 = *(const float2*)&W[(k + 3) * HD + f];
        #pragma unroll
        for (int m = 0; m < 8; m++) {
            float4 xk = *(const float4*)&xg[m * HD + k];
            acc[m].x += xk.x * w0.x; acc[m].y += xk.x * w0.y;
            acc[m].x += xk.y * w1.x; acc[m].y += xk.y * w1.y;
            acc[m].x += xk.z * w2.x; acc[m].y += xk.z * w2.y;
            acc[m].x += xk.w * w3.x; acc[m].y += xk.w * w3.y;
        }
    }

    float2 ats = *(const float2*)&atts[f];
    float2 atd = *(const float2*)&attd[f];
    #pragma unroll
    for (int m = 0; m < 8; m++) {
        int node = m0 + g * 8 + m;
        *(float2*)&h[(size_t)node * HD + f] = acc[m];
        float vs = acc[m].x * ats.x + acc[m].y * ats.y;
        float vd = acc[m].x * atd.x + acc[m].y * atd.y;
        #pragma unroll
        for (int off = 32; off > 0; off >>= 1) {
            vs += __shfl_down(vs, off);
            vd += __shfl_down(vd, off);
        }
        if (tt == 0) { a_s[node] = vs; a_d[node] = vd; }
    }
}

// ---------------- aggregation: block per dst node, float4 gathers ----------------
// 4 edge-slots x 32 lanes; lane q owns float4 q of the 128-float h row.
// exp fused (max-subtraction skipped: shift-invariant, e is O(1)).
// z > 0 structurally (self-loop per node).

__device__ __forceinline__ float edge_w(float as_v, float adn) {
    float e = as_v + adn;
    e = (e > 0.f) ? e : NEG * e;
    return __expf(e);
}

__global__ void k_agg1(const int* __restrict__ offsets,
                       const int* __restrict__ srclist,
                       const float* __restrict__ a_s,
                       const float* __restrict__ a_d,
                       const float4* __restrict__ h4,
                       const float* __restrict__ bias,
                       float* __restrict__ g) {
    __shared__ float accs[4][HD];
    __shared__ float zs[4];
    int node = blockIdx.x;
    int t = threadIdx.x;
    int slot = t >> 5, q = t & 31;
    int beg = offsets[node], end = offsets[node + 1];
    float adn = a_d[node];
    float4 acc = make_float4(0.f, 0.f, 0.f, 0.f);
    float z = 0.f;
    int p = beg + slot;
    for (; p + 4 < end; p += 8) {
        int s0 = srclist[p];
        int s1 = srclist[p + 4];
        float4 h0 = h4[(size_t)s0 * 32 + q];
        float4 h1 = h4[(size_t)s1 * 32 + q];
        float w0 = edge_w(a_s[s0], adn);
        float w1 = edge_w(a_s[s1], adn);
        z += w0 + w1;
        acc.x += w0 * h0.x + w1 * h1.x;
        acc.y += w0 * h0.y + w1 * h1.y;
        acc.z += w0 * h0.z + w1 * h1.z;
        acc.w += w0 * h0.w + w1 * h1.w;
    }
    if (p < end) {
        int s0 = srclist[p];
        float4 h0 = h4[(size_t)s0 * 32 + q];
        float w0 = edge_w(a_s[s0], adn);
        z += w0;
        acc.x += w0 * h0.x; acc.y += w0 * h0.y;
        acc.z += w0 * h0.z; acc.w += w0 * h0.w;
    }
    *(float4*)&accs[slot][q * 4] = acc;
    if (q == 0) zs[slot] = z;
    __syncthreads();
    float v = accs[0][t] + accs[1][t] + accs[2][t] + accs[3][t];
    float zz = zs[0] + zs[1] + zs[2] + zs[3];
    float o = v / zz + bias[t];
    g[(size_t)node * HD + t] = (o > 0.f) ? o : 0.f;   // relu
}

// layer-2 aggregation fused with reduce_dim: r[n] = relu(agg+b2) . Wr + br
__global__ void k_agg2(const int* __restrict__ offsets,
                       const int* __restrict__ srclist,
                       const float* __restrict__ a_s,
                       const float* __restrict__ a_d,
                       const float4* __restrict__ h4,
                       const float* __restrict__ bias,
                       const float* __restrict__ Wr,
                       const float* __restrict__ br,
                       float* __restrict__ r) {
    __shared__ float accs[4][HD];
    __shared__ float zs[4];
    __shared__ float red[2];
    int node = blockIdx.x;
    int t = threadIdx.x;
    int slot = t >> 5, q = t & 31;
    int beg = offsets[node], end = offsets[node + 1];
    float adn = a_d[node];
    float4 acc = make_float4(0.f, 0.f, 0.f, 0.f);
    float z = 0.f;
    int p = beg + slot;
    for (; p + 4 < end; p += 8) {
        int s0 = srclist[p];
        int s1 = srclist[p + 4];
        float4 h0 = h4[(size_t)s0 * 32 + q];
        float4 h1 = h4[(size_t)s1 * 32 + q];
        float w0 = edge_w(a_s[s0], adn);
        float w1 = edge_w(a_s[s1], adn);
        z += w0 + w1;
        acc.x += w0 * h0.x + w1 * h1.x;
        acc.y += w0 * h0.y + w1 * h1.y;
        acc.z += w0 * h0.z + w1 * h1.z;
        acc.w += w0 * h0.w + w1 * h1.w;
    }
    if (p < end) {
        int s0 = srclist[p];
        float4 h0 = h4[(size_t)s0 * 32 + q];
        float w0 = edge_w(a_s[s0], adn);
        z += w0;
        acc.x += w0 * h0.x; acc.y += w0 * h0.y;
        acc.z += w0 * h0.z; acc.w += w0 * h0.w;
    }
    *(float4*)&accs[slot][q * 4] = acc;
    if (q == 0) zs[slot] = z;
    __syncthreads();
    float v = accs[0][t] + accs[1][t] + accs[2][t] + accs[3][t];
    float zz = zs[0] + zs[1] + zs[2] + zs[3];
    float o = v / zz + bias[t];
    o = (o > 0.f) ? o : 0.f;
    float part = o * Wr[t];
    #pragma unroll
    for (int off = 32; off > 0; off >>= 1) part += __shfl_down(part, off);
    if ((t & 63) == 0) red[t >> 6] = part;
    __syncthreads();
    if (t == 0) r[node] = red[0] + red[1] + br[0];
}

// ---------------- classifier: out[c] = sum_n r[n]*Wc[n,c] + bc[c] ----------------

__global__ void k_cls(const float* __restrict__ r,
                      const float* __restrict__ Wc,
                      const float* __restrict__ bc,
                      float* __restrict__ out) {
    __shared__ float r0[256], r1[256];
    int t = threadIdx.x;
    float c0 = 0.f, c1 = 0.f;
    for (int n = t; n < NN; n += 256) {
        float rv = r[n];
        c0 += rv * Wc[2 * n];
        c1 += rv * Wc[2 * n + 1];
    }
    r0[t] = c0; r1[t] = c1;
    __syncthreads();
    for (int off = 128; off > 0; off >>= 1) {
        if (t < off) { r0[t] += r0[t + off]; r1[t] += r1[t + off]; }
        __syncthreads();
    }
    if (t == 0) {
        out[0] = r0[0] + bc[0];
        out[1] = r1[0] + bc[1];
    }
}

// ---------------- launch ----------------

extern "C" void kernel_launch(void* const* d_in, const int* in_sizes, int n_in,
                              void* d_out, int out_size, void* d_ws, size_t ws_size,
                              hipStream_t stream) {
    const float* x    = (const float*)d_in[0];
    const int*   ei   = (const int*)d_in[1];
    const float* W1   = (const float*)d_in[2];
    const float* as1  = (const float*)d_in[3];
    const float* ad1  = (const float*)d_in[4];
    const float* b1   = (const float*)d_in[5];
    const float* W2   = (const float*)d_in[6];
    const float* as2  = (const float*)d_in[7];
    const float* ad2  = (const float*)d_in[8];
    const float* b2   = (const float*)d_in[9];
    const float* Wr   = (const float*)d_in[10];
    const float* br   = (const float*)d_in[11];
    const float* Wc   = (const float*)d_in[12];
    const float* bc   = (const float*)d_in[13];
    float* out = (float*)d_out;

    // workspace layout
    float* h    = (float*)d_ws;                  // NN*HD (16B aligned)
    float* g1   = h + (size_t)NN * HD;           // NN*HD
    float* a_s  = g1 + (size_t)NN * HD;          // NN
    float* a_d  = a_s + NN;                      // NN
    float* r    = a_d + NN;                      // NN
    int* counts  = (int*)(r + NN);               // NN
    int* offsets = counts + NN;                  // NN+1
    int* cursor  = offsets + NN + 1;             // NN
    int* srclist = cursor + NN;                  // ET

    const int TPB = 256;
    const int gET = (ET + TPB - 1) / TPB;
    const int gNN = (NN + TPB - 1) / TPB;

    // CSR build (shared by both layers)
    k_zero_i<<<gNN, TPB, 0, stream>>>(counts, NN);
    k_hist<<<gET, TPB, 0, stream>>>(ei, counts);
    k_scan<<<1, 256, 0, stream>>>(counts, offsets, cursor);
    k_scatter<<<gET, TPB, 0, stream>>>(ei, cursor, srclist);

    // layer 1
    k_gemm1<<<NN / 16, 128, 0, stream>>>(x, W1, as1, ad1, h, a_s, a_d);
    k_agg1<<<NN, 128, 0, stream>>>(offsets, srclist, a_s, a_d, (const float4*)h, b1, g1);

    // layer 2
    k_gemm2<<<NN / 16, 128, 0, stream>>>(g1, W2, as2, ad2, h, a_s, a_d);
    k_agg2<<<NN, 128, 0, stream>>>(offsets, srclist, a_s, a_d, (const float4*)h, b2, Wr, br, r);

    // classifier
    k_cls<<<1, 256, 0, stream>>>(r, Wc, bc, out);
}